// Round 11
// baseline (442.401 us; speedup 1.0000x reference)
//
#include <hip/hip_runtime.h>
#include <stdint.h>
#include <math.h>

#define T 1024            // block size
#define NB 2048           // histogram bins
#define SPLIT 4           // slots per row; grid = SPLIT*B = 512
#define NW 16             // waves per block
#define LW 256            // per-wave candidate cap (phase C uses >>8)
#define NSEG (SPLIT*NW)   // 64 segments per row
#define CAND2 2048
#define PS 4096           // presample count per slot
#define L2E 1.44269504088896f

typedef float vfloat4 __attribute__((ext_vector_type(4)));
typedef unsigned long long ull;

__device__ __forceinline__ unsigned fkey(float f) {
    unsigned u = __float_as_uint(f);
    return (u & 0x80000000u) ? ~u : (u | 0x80000000u);
}
__device__ __forceinline__ float funkey(unsigned k) {
    unsigned u = (k & 0x80000000u) ? (k ^ 0x80000000u) : ~k;
    return __uint_as_float(u);
}
__device__ __forceinline__ ull packkv(unsigned k, unsigned idx) {
    return ((ull)k << 32) | (ull)(~idx);    // ~idx: desc key sort => asc idx ties
}

// in-place suffix sum of h[0..NB), 1024 threads.
__device__ __forceinline__ void suffix_scan_2048(unsigned* h, unsigned* wscr, int tid)
{
    const int lane = tid & 63, w = tid >> 6;
    const int i0 = 2047 - 2 * tid;
    const int i1 = 2046 - 2 * tid;
    unsigned a = h[i0], b = h[i1];
    unsigned s = a + b;
    unsigned inc = s;
    #pragma unroll
    for (int d = 1; d < 64; d <<= 1) { unsigned o = __shfl_up(inc, d); if (lane >= d) inc += o; }
    if (lane == 63) wscr[w] = inc;
    __syncthreads();
    if (w == 0) {
        unsigned v = (lane < 16) ? wscr[lane] : 0u;
        unsigned vi = v;
        #pragma unroll
        for (int d = 1; d < 16; d <<= 1) { unsigned o = __shfl_up(vi, d); if (lane >= d) vi += o; }
        if (lane < 16) wscr[16 + lane] = vi - v;
    }
    __syncthreads();
    unsigned off = wscr[16 + w] + (inc - s);
    h[i0] = off + a;
    h[i1] = off + a + b;
    __syncthreads();
}

__global__ __launch_bounds__(T, 8)
void fused(const float* __restrict__ logits,
           const float* __restrict__ temps,
           const int* __restrict__ top_ks,
           const float* __restrict__ top_ps,
           const float* __restrict__ min_ps,
           const float* __restrict__ uvec,
           unsigned* __restrict__ ws_arrive, // [B] zeroed by memset
           float* __restrict__ ws_cy,
           float* __restrict__ ws_z,
           unsigned* __restrict__ ws_cut,
           unsigned* __restrict__ ws_wcnt,
           unsigned* __restrict__ ws_maxk,
           ull* __restrict__ ws_cand,
           float* __restrict__ out_tok,
           float* __restrict__ out_probs,
           int V, int Vq, int B)
{
    const int slot = blockIdx.x;
    const int b = slot / SPLIT, s = slot % SPLIT;
    const int tid = threadIdx.x, lane = tid & 63, wv = tid >> 6;
    const int start = s * Vq;
    const int len = min(Vq, V - start);
    const float invT = 1.0f / temps[b];

    // ---- LDS carve (37.3 KB; 2 blocks/CU) ----
    __shared__ __align__(16) char smem[37120];
    ull*            cand2 = (ull*)smem;                         // [2048] 16 KB
    unsigned*       hist  = (unsigned*)(smem + 16384);          // [2049]
    unsigned short* cnts  = (unsigned short*)(smem + 24584);    // [2048]
    float*          sh_p  = (float*)(smem + 28680);             // [1024]
    float*          sh_c  = (float*)(smem + 32776);             // [1024]
    unsigned short* segc  = (unsigned short*)(smem + 36872);    // [NSEG]
    __shared__ unsigned uscr[32];
    __shared__ float fws[32];
    __shared__ float fred[2 * NW];
    __shared__ unsigned ucnt[NW];
    __shared__ unsigned scnt;
    __shared__ int sh_i1, sh_i2, sh_win;
    __shared__ unsigned sh_u1;

    // ================= Phase A: presample cut =================
    float cutval = 1e30f; float Cy_loc = -1e30f; unsigned cutkey = 0xFFFFFFFFu;
    if (len > 0) {
        for (int i = tid; i < NB; i += T) hist[i] = 0;
        if (tid == 0) sh_i1 = 0;
        __syncthreads();
        const float* __restrict__ row = logits + (size_t)b * V + start;
        const vfloat4* __restrict__ row4 = (const vfloat4*)row;
        const int nps = min(len, PS);
        const int np4 = nps >> 2;
        float m0 = -1e30f;
        for (int i = tid; i < np4; i += T) {
            vfloat4 v = row4[i];
            #pragma unroll
            for (int j = 0; j < 4; ++j) {
                float lv = v[j];
                m0 = fmaxf(m0, lv);
                atomicAdd(&hist[fkey(lv) >> 21], 1u);
            }
        }
        for (int i = (np4 << 2) + tid; i < nps; i += T) {
            float lv = row[i];
            m0 = fmaxf(m0, lv);
            atomicAdd(&hist[fkey(lv) >> 21], 1u);
        }
        #pragma unroll
        for (int d = 32; d > 0; d >>= 1) m0 = fmaxf(m0, __shfl_down(m0, d));
        if (lane == 0) fred[wv] = m0;
        __syncthreads();
        if (tid == 0) {
            float mm = fred[0];
            for (int j = 1; j < NW; ++j) mm = fmaxf(mm, fred[j]);
            fws[0] = mm;
        }
        __syncthreads();
        const float m0max = fws[0];
        suffix_scan_2048(hist, uscr, tid);
        int K = top_ks[b]; K = max(K, 1); K = min(K, 1024);
        float sexp = (float)K * (float)nps / (float)V;
        unsigned TGT = (unsigned)(sexp + 6.0f * sqrtf(sexp) + 16.5f);
        if (TGT > (unsigned)nps) TGT = (unsigned)nps;
        for (int e = tid; e < NB; e += T) {
            unsigned Se = hist[e];
            unsigned Sn = (e < NB - 1) ? hist[e + 1] : 0u;
            if (Se >= TGT && Sn < TGT) sh_i1 = e;   // unique writer
        }
        __syncthreads();
        cutkey = (unsigned)sh_i1 << 21;
        cutval = funkey(cutkey);
        Cy_loc = m0max * invT;
        if (tid == 0) { ws_cut[slot] = cutkey; ws_cy[slot] = Cy_loc; }
    } else {
        if (tid == 0) { ws_cut[slot] = 0xFFFFFFFFu; ws_cy[slot] = -1e30f; }
    }

    // ================= Phase B: stream =================
    if (len > 0) {
        const float* __restrict__ row = logits + (size_t)b * V + start;
        const vfloat4* __restrict__ row4 = (const vfloat4*)row;
        const int L4 = len >> 2;
        {
            float* __restrict__ orow = out_probs + (size_t)b * V + start;
            vfloat4* __restrict__ orow4 = (vfloat4*)orow;
            const vfloat4 z4 = (vfloat4)0.0f;
            for (int i = tid; i < L4; i += T) __builtin_nontemporal_store(z4, &orow4[i]);
            for (int i = (L4 << 2) + tid; i < len; i += T) __builtin_nontemporal_store(0.0f, &orow[i]);
        }
        const float ca = invT * L2E;
        const float cb = -Cy_loc * L2E;
        ull* gw = ws_cand + ((size_t)slot * NW + wv) * LW;
        const ull lmask = (1ull << lane) - 1ull;
        unsigned wcnt = 0;
        float z0 = 0.0f, z1 = 0.0f, z2 = 0.0f, z3 = 0.0f, mb = -1e30f;

        #define E4(v) (exp2f(fmaf((v)[0], ca, cb)) + exp2f(fmaf((v)[1], ca, cb)) \
                     + exp2f(fmaf((v)[2], ca, cb)) + exp2f(fmaf((v)[3], ca, cb)))
        #define GE1(x, gi) do {                                                 \
            bool p = (x) >= cutval;                                             \
            ull bm = __ballot(p);                                               \
            if (bm) {                                                           \
                mb = fmaxf(mb, p ? (x) : -1e30f);                               \
                unsigned pos = wcnt + (unsigned)__popcll(bm & lmask);           \
                if (p && pos < LW) gw[pos] = packkv(fkey(x), (unsigned)(gi));   \
                wcnt += (unsigned)__popcll(bm);                                 \
            }                                                                   \
        } while (0)
        #define GE4(v, ii) do {                                                 \
            unsigned gbase = (unsigned)(start + ((ii) << 2));                   \
            GE1((v)[0], gbase + 0); GE1((v)[1], gbase + 1);                     \
            GE1((v)[2], gbase + 2); GE1((v)[3], gbase + 3);                     \
        } while (0)

        int k = 0;
        for (; (k + 4) * T <= L4; k += 4) {
            int i0 = k * T + tid;
            vfloat4 va = row4[i0];
            vfloat4 vb = row4[i0 + T];
            vfloat4 vc = row4[i0 + 2 * T];
            vfloat4 vd = row4[i0 + 3 * T];
            z0 += E4(va); z1 += E4(vb); z2 += E4(vc); z3 += E4(vd);
            GE4(va, i0); GE4(vb, i0 + T); GE4(vc, i0 + 2 * T); GE4(vd, i0 + 3 * T);
        }
        for (; k * T + (wv << 6) < L4; ++k) {
            int idx = k * T + tid;
            vfloat4 v = (idx < L4) ? row4[idx] : (vfloat4)(-1e30f);
            z0 += E4(v);
            GE4(v, idx);
        }
        for (int j = (L4 << 2) + tid; j < len; j += T) {
            float lv = row[j];
            z0 += exp2f(fmaf(lv, ca, cb));
            GE1(lv, start + j);
        }
        #undef E4
        #undef GE1
        #undef GE4

        float z = (z0 + z1) + (z2 + z3);
        __syncthreads();
        #pragma unroll
        for (int d = 32; d > 0; d >>= 1) {
            z += __shfl_down(z, d);
            mb = fmaxf(mb, __shfl_down(mb, d));
        }
        if (lane == 0) {
            fred[wv] = z; fred[NW + wv] = mb; ucnt[wv] = wcnt;
            ws_wcnt[slot * NW + wv] = wcnt;
        }
        __syncthreads();
        if (tid == 0) {
            float zz = 0.0f, mm = -1e30f; unsigned tot = 0;
            for (int j = 0; j < NW; ++j) { zz += fred[j]; mm = fmaxf(mm, fred[NW + j]); tot += ucnt[j]; }
            ws_z[slot] = zz;
            ws_maxk[slot] = tot ? fkey(mm) : 0u;
        }
    } else {
        if (lane == 0) ws_wcnt[slot * NW + wv] = 0u;
        if (tid == 0) { ws_z[slot] = 0.0f; ws_maxk[slot] = 0u; }
    }

    // ========== arrival: last block of this row runs Phase C ==========
    __syncthreads();
    __threadfence();                               // release all ws writes
    if (tid == 0) {
        unsigned old = atomicAdd(&ws_arrive[b], 1u);
        sh_win = (old == (unsigned)(SPLIT - 1));
    }
    __syncthreads();
    if (!sh_win) return;
    __threadfence();                               // acquire siblings' writes

    // ================= Phase C: sample row b =================
    int Korig = top_ks[b]; Korig = max(Korig, 1); Korig = min(Korig, 1024);
    const unsigned Ku = (unsigned)Korig;
    const float top_p = top_ps[b], min_p = min_ps[b], uval = uvec[b];

    bool myfb = false;
    for (int i = tid; i < NSEG; i += T) {
        unsigned c = ws_wcnt[b * NSEG + i];
        if (c > (unsigned)LW) myfb = true;
        segc[i] = (unsigned short)min(c, (unsigned)LW);
    }
    float Cy[SPLIT], zq[SPLIT];
    unsigned cutq[SPLIT], mkq[SPLIT];
    #pragma unroll
    for (int q = 0; q < SPLIT; ++q) {
        int sl = b * SPLIT + q;
        Cy[q] = ws_cy[sl]; zq[q] = ws_z[sl];
        cutq[q] = ws_cut[sl]; mkq[q] = ws_maxk[sl];
    }
    __syncthreads();
    unsigned cntq[SPLIT];
    #pragma unroll
    for (int q = 0; q < SPLIT; ++q) {
        unsigned t = 0;
        #pragma unroll
        for (int v = 0; v < NW; ++v) t += segc[q * NW + v];
        cntq[q] = t;
    }
    float Y = -1e30f;
    #pragma unroll
    for (int q = 0; q < SPLIT; ++q) if (zq[q] > 0.0f) Y = fmaxf(Y, Cy[q]);
    float Z = 0.0f;
    #pragma unroll
    for (int q = 0; q < SPLIT; ++q)
        if (zq[q] > 0.0f) Z += zq[q] * exp2f((Cy[q] - Y) * L2E);

    unsigned cutmax = 0, mincut = 0xFFFFFFFFu, maxkey = 0;
    #pragma unroll
    for (int q = 0; q < SPLIT; ++q) {
        if (cntq[q] > 0u) {
            if (!isfinite(zq[q])) myfb = true;
            cutmax = max(cutmax, cutq[q]);
            mincut = min(mincut, cutq[q]);
            maxkey = max(maxkey, mkq[q]);
        }
    }
    if (mincut == 0xFFFFFFFFu || !isfinite(Z) || Z <= 0.0f) myfb = true;
    bool fb = __syncthreads_or((int)myfb) != 0;

    unsigned Tkeyb = 0;
    int count = 0, bstar = 0, shift = 0;
    const unsigned base = mincut;
    const ull* cbase = ws_cand + (size_t)b * NSEG * LW;

    if (!fb) {
        const unsigned range = maxkey - base;
        while ((range >> shift) > (unsigned)(NB - 1)) shift++;
        for (int i = tid; i <= NB; i += T) hist[i] = 0;
        if (tid == 0) { sh_i1 = -1; scnt = 0; }
        __syncthreads();
        for (int v = tid; v < NSEG * LW; v += T) {
            int off = v & (LW - 1);
            int seg = v >> 8;                               // LW == 256
            if (off < (int)segc[seg]) {
                ull e = cbase[v];
                atomicAdd(&hist[((unsigned)(e >> 32) - base) >> shift], 1u);
            }
        }
        __syncthreads();
        unsigned fat = 0;
        for (int i = tid; i < NB; i += T) {
            unsigned h = hist[i];
            cnts[i] = (unsigned short)h;
            fat = max(fat, h);
        }
        #pragma unroll
        for (int d = 32; d > 0; d >>= 1) fat = max(fat, __shfl_down(fat, d));
        if (lane == 0) uscr[wv] = fat;
        __syncthreads();
        if (tid == 0) {
            unsigned m2 = 0;
            for (int j = 0; j < 16; ++j) m2 = max(m2, uscr[j]);
            uscr[16] = m2;
        }
        __syncthreads();
        if (uscr[16] > 64u) fb = true;
    }
    if (!fb) {
        suffix_scan_2048(hist, uscr, tid);
        for (int e = tid; e < NB; e += T) {
            unsigned Se = hist[e], Sn = (e < NB - 1) ? hist[e + 1] : 0u;
            if (Se >= Ku && Sn < Ku) { sh_i1 = e; sh_u1 = Se; }
        }
        __syncthreads();
        if (sh_i1 < 0) fb = true;
        else {
            bstar = sh_i1;
            count = (int)sh_u1;
            Tkeyb = base + ((unsigned)bstar << shift);
            if (Tkeyb < cutmax || count > CAND2) fb = true;
        }
    }
    if (!fb) {
        for (int v = tid; v < NSEG * LW; v += T) {
            int off = v & (LW - 1);
            int seg = v >> 8;
            if (off < (int)segc[seg]) {
                ull e = cbase[v];
                unsigned k = (unsigned)(e >> 32);
                if (k >= Tkeyb) {
                    unsigned bin = (k - base) >> shift;
                    unsigned pos = atomicAdd(&hist[bin + 1], 1u);
                    cand2[pos] = e;
                }
            }
        }
        __syncthreads();
        for (int e = bstar + tid; e < NB; e += T) {
            int c = (int)cnts[e];
            if (c >= 2) {
                int st = (int)hist[e + 1] - c;
                for (int x = 1; x < c; ++x) {
                    ull key = cand2[st + x];
                    int y = x - 1;
                    while (y >= 0 && cand2[st + y] < key) { cand2[st + y + 1] = cand2[st + y]; --y; }
                    cand2[st + y + 1] = key;
                }
            }
        }
        __syncthreads();
    }

    if (fb) {
        const float* __restrict__ row = logits + (size_t)b * V;
        float m = -1e30f, z = 0.0f;
        for (int i = tid; i < V; i += T) {
            float y = row[i] * invT;
            float nm = fmaxf(m, y);
            z = z * exp2f((m - nm) * L2E) + exp2f((y - nm) * L2E);
            m = nm;
        }
        sh_p[tid] = m; sh_c[tid] = z;
        __syncthreads();
        for (int d = T >> 1; d > 0; d >>= 1) {
            if (tid < d) {
                float m1 = sh_p[tid], z1 = sh_c[tid];
                float m2 = sh_p[tid + d], z2 = sh_c[tid + d];
                float mm = fmaxf(m1, m2);
                sh_c[tid] = z1 * exp2f((m1 - mm) * L2E) + z2 * exp2f((m2 - mm) * L2E);
                sh_p[tid] = mm;
            }
            __syncthreads();
        }
        Y = sh_p[0]; Z = sh_c[0];
        __syncthreads();
        for (int i = tid; i < NB; i += T) hist[i] = 0;
        if (tid == 0) { sh_i1 = 0; sh_i2 = 0; sh_u1 = 0; }
        __syncthreads();
        for (int i = tid; i < V; i += T) atomicAdd(&hist[fkey(row[i]) >> 21], 1u);
        __syncthreads();
        suffix_scan_2048(hist, uscr, tid);
        for (int e = tid; e < NB; e += T) {
            unsigned Se = hist[e], Sn = (e < NB - 1) ? hist[e + 1] : 0u;
            if (Se >= Ku && Sn < Ku) { sh_i1 = e; sh_u1 = Sn; }
        }
        __syncthreads();
        int b1 = sh_i1;
        unsigned cab = sh_u1;
        for (int i = tid; i < NB; i += T) hist[i] = 0;
        __syncthreads();
        for (int i = tid; i < V; i += T) {
            unsigned k = fkey(row[i]);
            if ((int)(k >> 21) == b1) atomicAdd(&hist[(k >> 10) & (NB - 1)], 1u);
        }
        __syncthreads();
        suffix_scan_2048(hist, uscr, tid);
        for (int e = tid; e < NB; e += T) {
            unsigned Se = cab + hist[e];
            unsigned Sn = cab + ((e < NB - 1) ? hist[e + 1] : 0u);
            if (Se >= Ku && Sn < Ku) sh_i2 = e;
        }
        __syncthreads();
        unsigned Tkey = ((unsigned)b1 << 21) | ((unsigned)sh_i2 << 10);
        if (tid == 0) scnt = 0;
        __syncthreads();
        for (int i = tid; i < V; i += T) {
            unsigned k = fkey(row[i]);
            if (k >= Tkey) {
                unsigned pos = atomicAdd(&scnt, 1u);
                if (pos < CAND2) cand2[pos] = packkv(k, (unsigned)i);
            }
        }
        __syncthreads();
        count = (scnt < (unsigned)CAND2) ? (int)scnt : CAND2;

        int n_sort = 1;
        while (n_sort < count) n_sort <<= 1;
        for (int i = tid; i < n_sort; i += T)
            if (i >= count) cand2[i] = 0ull;
        __syncthreads();
        for (int kk = 2; kk <= n_sort; kk <<= 1) {
            for (int j = kk >> 1; j > 0; j >>= 1) {
                for (int i = tid; i < n_sort; i += T) {
                    int ixj = i ^ j;
                    if (ixj > i) {
                        ull a = cand2[i], c = cand2[ixj];
                        bool up = (i & kk) == 0;
                        if (up ? (a < c) : (a > c)) { cand2[i] = c; cand2[ixj] = a; }
                    }
                }
                __syncthreads();
            }
        }
    }

    int K = min(Korig, count);

    float pv = 0.0f;
    if (tid < K) {
        unsigned k = (unsigned)(cand2[tid] >> 32);
        pv = exp2f((funkey(k) * invT - Y) * L2E) / Z;
    }
    float inc = pv;
    #pragma unroll
    for (int d = 1; d < 64; d <<= 1) { float o = __shfl_up(inc, d); if (lane >= d) inc += o; }
    if (lane == 63) fws[wv] = inc;
    __syncthreads();
    if (wv == 0) {
        float v = (lane < 16) ? fws[lane] : 0.0f;
        float vi = v;
        #pragma unroll
        for (int d = 1; d < 16; d <<= 1) { float o = __shfl_up(vi, d); if (lane >= d) vi += o; }
        if (lane < 16) fws[16 + lane] = vi - v;
    }
    __syncthreads();
    float cum = inc + fws[16 + wv];
    sh_p[tid] = pv;
    sh_c[tid] = cum;
    if (tid == 0) sh_i1 = K;
    __syncthreads();

    if (tid < K) {
        float excl = cum - pv;            // cumsum BEFORE masking, as reference
        if (excl > top_p) atomicMin(&sh_i1, tid);
    }
    __syncthreads();
    int n1 = sh_i1;
    float thr = sh_p[0] * min_p;
    if (tid == 0) sh_i2 = n1;
    __syncthreads();
    if (tid < n1 && sh_p[tid] < thr) atomicMin(&sh_i2, tid);
    __syncthreads();
    int nf = sh_i2;                        // >= 1
    float total = sh_c[nf - 1];

    int pred = (tid < nf) && ((sh_c[tid] / total) < uval);
    int rank = __syncthreads_count(pred);
    if (rank > nf - 1) rank = nf - 1;
    if (rank < 0) rank = 0;
    if (tid == 0)
        out_tok[b] = (float)(~(unsigned)(cand2[rank] & 0xFFFFFFFFull));

    if (tid < nf) {
        unsigned idx = ~(unsigned)(cand2[tid] & 0xFFFFFFFFull);
        out_probs[(size_t)b * V + idx] = sh_p[tid] / total;
    }
}

extern "C" void kernel_launch(void* const* d_in, const int* in_sizes, int n_in,
                              void* d_out, int out_size, void* d_ws, size_t ws_size,
                              hipStream_t stream) {
    const float* logits = (const float*)d_in[0];
    const float* temps  = (const float*)d_in[1];
    const int*   top_ks = (const int*)d_in[2];
    const float* top_ps = (const float*)d_in[3];
    const float* min_ps = (const float*)d_in[4];
    const float* u      = (const float*)d_in[5];
    int B = in_sizes[1];
    int V = in_sizes[0] / B;
    float* out_tok   = (float*)d_out;
    float* out_probs = out_tok + B;

    int Vq = (((V + SPLIT - 1) / SPLIT) + 3) & ~3;

    char* ws = (char*)d_ws;
    size_t off = 0;
    auto take = [&](size_t bytes) { char* p = ws + off; off = (off + bytes + 255) & ~(size_t)255; return p; };
    unsigned* ws_arrive = (unsigned*)take((size_t)B * sizeof(unsigned));
    float*    ws_cy   = (float*)take((size_t)B * SPLIT * sizeof(float));
    float*    ws_z    = (float*)take((size_t)B * SPLIT * sizeof(float));
    unsigned* ws_cut  = (unsigned*)take((size_t)B * SPLIT * sizeof(unsigned));
    unsigned* ws_wcnt = (unsigned*)take((size_t)B * NSEG * sizeof(unsigned));
    unsigned* ws_maxk = (unsigned*)take((size_t)B * SPLIT * sizeof(unsigned));
    ull*      ws_cand = (ull*)take((size_t)B * NSEG * LW * sizeof(ull));
    (void)ws_size;

    // zero the arrival counters (poisoned 0xAA before every timed launch)
    hipMemsetAsync(ws_arrive, 0, (size_t)B * sizeof(unsigned), stream);

    fused<<<dim3(SPLIT * B), dim3(T), 0, stream>>>(
        logits, temps, top_ks, top_ps, min_ps, u,
        ws_arrive, ws_cy, ws_z, ws_cut, ws_wcnt, ws_maxk, ws_cand,
        out_tok, out_probs, V, Vq, B);
}